// Round 1
// baseline (513.404 us; speedup 1.0000x reference)
//
#include <hip/hip_runtime.h>
#include <math.h>

#define ND 3072
#define EDG 100000

// ---------------- workspace layout (float offsets) ----------------
enum : size_t {
  OFF_H1    = 0,                          // 3072*512
  OFF_H2    = OFF_H1 + 3072*512,          // 3072*256
  OFF_FEATD = OFF_H2 + 3072*256,          // 3072*128
  OFF_FEATT = OFF_FEATD + 3072*128,       // 3072*128
  OFF_WHD   = OFF_FEATT + 3072*128,       // 3072*16
  OFF_WHT   = OFF_WHD + 3072*16,
  OFF_S1D   = OFF_WHT + 3072*16,
  OFF_S2D   = OFF_S1D + 3072,
  OFF_S1T   = OFF_S2D + 3072,
  OFF_S2T   = OFF_S1T + 3072,
  OFF_HEADD = OFF_S2T + 3072,             // [2,2,3072,16]
  OFF_HEADT = OFF_HEADD + 4*3072*16,
  OFF_PGD   = OFF_HEADT + 4*3072*16,      // [2,3072,16]
  OFF_PGT   = OFF_PGD + 2*3072*16,
  OFF_F16D  = OFF_PGT + 2*3072*16,        // [3072,16]
  OFF_F16T  = OFF_F16D + 3072*16,
  OFF_AWS   = OFF_F16T + 3072*16,         // [16][128]
  OFF_W1D   = OFF_AWS + 2048,             // [16][64]
  OFF_W1T   = OFF_W1D + 1024,             // [16][64]
  OFF_AOM   = OFF_W1T + 1024,             // [16]
  OFF_DOTSD = OFF_AOM + 16,               // [2][3072]
  OFF_DOTST = OFF_DOTSD + 2*3072,
  OFF_GSUMD = OFF_DOTST + 2*3072,         // [2] (+pad)
  OFF_GSUMT = OFF_GSUMD + 4,
  WS_TOTAL  = OFF_GSUMT + 4
};

// ---------------- fused GEMM + bias + relu:  C[M,N] = relu(A[M,K]@B[K,N]+b) ----------------
__global__ __launch_bounds__(256) void gemm_relu(const float* __restrict__ A,
    const float* __restrict__ B, const float* __restrict__ bias,
    float* __restrict__ C, int M, int N, int K)
{
  __shared__ float AsT[32][68];   // K-major A tile, padded for banks + 16B alignment
  __shared__ float Bs[32][64];
  const int t  = threadIdx.x;
  const int tx = t & 15, ty = t >> 4;
  const int row0 = blockIdx.y << 6, col0 = blockIdx.x << 6;
  float acc[4][4] = {};
  const int ar0 = t >> 3, ac0 = (t & 7) << 2;   // A tile: 64 rows x 32 k
  const int ar1 = ar0 + 32;
  const int br0 = t >> 4, bc0 = (t & 15) << 2;  // B tile: 32 k x 64 cols
  const int br1 = br0 + 16;
  for (int k0 = 0; k0 < K; k0 += 32) {
    float4 a0 = *(const float4*)&A[(size_t)(row0 + ar0) * K + k0 + ac0];
    float4 a1 = *(const float4*)&A[(size_t)(row0 + ar1) * K + k0 + ac0];
    float4 b0 = *(const float4*)&B[(size_t)(k0 + br0) * N + col0 + bc0];
    float4 b1 = *(const float4*)&B[(size_t)(k0 + br1) * N + col0 + bc0];
    __syncthreads();
    AsT[ac0+0][ar0]=a0.x; AsT[ac0+1][ar0]=a0.y; AsT[ac0+2][ar0]=a0.z; AsT[ac0+3][ar0]=a0.w;
    AsT[ac0+0][ar1]=a1.x; AsT[ac0+1][ar1]=a1.y; AsT[ac0+2][ar1]=a1.z; AsT[ac0+3][ar1]=a1.w;
    *(float4*)&Bs[br0][bc0] = b0;
    *(float4*)&Bs[br1][bc0] = b1;
    __syncthreads();
    #pragma unroll
    for (int kk = 0; kk < 32; ++kk) {
      float4 av = *(const float4*)&AsT[kk][ty << 2];
      float4 bv = *(const float4*)&Bs[kk][tx << 2];
      acc[0][0] += av.x*bv.x; acc[0][1] += av.x*bv.y; acc[0][2] += av.x*bv.z; acc[0][3] += av.x*bv.w;
      acc[1][0] += av.y*bv.x; acc[1][1] += av.y*bv.y; acc[1][2] += av.y*bv.z; acc[1][3] += av.y*bv.w;
      acc[2][0] += av.z*bv.x; acc[2][1] += av.z*bv.y; acc[2][2] += av.z*bv.z; acc[2][3] += av.z*bv.w;
      acc[3][0] += av.w*bv.x; acc[3][1] += av.w*bv.y; acc[3][2] += av.w*bv.z; acc[3][3] += av.w*bv.w;
    }
  }
  float4 bb = *(const float4*)&bias[col0 + (tx << 2)];
  #pragma unroll
  for (int i = 0; i < 4; ++i) {
    int row = row0 + (ty << 2) + i;
    float4 o;
    o.x = fmaxf(acc[i][0] + bb.x, 0.f);
    o.y = fmaxf(acc[i][1] + bb.y, 0.f);
    o.z = fmaxf(acc[i][2] + bb.z, 0.f);
    o.w = fmaxf(acc[i][3] + bb.w, 0.f);
    *(float4*)&C[(size_t)row * N + col0 + (tx << 2)] = o;
  }
}

// ---------------- wh = feats@gat_w [N,16]; s1 = wh@a1; s2 = wh@a2 ----------------
__global__ __launch_bounds__(256) void wh_kernel(const float* __restrict__ feat,
    const float* __restrict__ gw, const float* __restrict__ ga1, const float* __restrict__ ga2,
    float* __restrict__ wh, float* __restrict__ s1, float* __restrict__ s2)
{
  __shared__ float W[128*16];
  __shared__ float A1[16], A2[16];
  const int t = threadIdx.x;
  for (int i = t; i < 2048; i += 256) W[i] = gw[i];
  if (t < 16) { A1[t] = ga1[t]; A2[t] = ga2[t]; }
  __syncthreads();
  const int n = (blockIdx.x << 4) + (t >> 4);
  const int d = t & 15;
  const float* f = feat + (size_t)n * 128;
  float acc = 0.f;
  #pragma unroll 8
  for (int k = 0; k < 128; ++k) acc += f[k] * W[k*16 + d];
  wh[(size_t)n*16 + d] = acc;
  float v1 = acc * A1[d], v2 = acc * A2[d];
  #pragma unroll
  for (int off = 8; off; off >>= 1) { v1 += __shfl_xor(v1, off); v2 += __shfl_xor(v2, off); }
  if (d == 0) { s1[n] = v1; s2[n] = v2; }
}

// ---------------- attention scan: one wave per (g,r,n) row ----------------
template<bool ALL>
__device__ __forceinline__ void scan_row(const float* __restrict__ brow,
    const float* __restrict__ s2, const float* __restrict__ wh,
    float s1v, int lane, float& m, float& s, float acc[16])
{
  for (int i = 0; i < ND/256; ++i) {          // 12 float4 per lane
    const int j4 = lane + (i << 6);
    float4 b = ((const float4*)brow)[j4];
    #pragma unroll
    for (int c = 0; c < 4; ++c) {
      float bv = (c==0) ? b.x : ((c==1) ? b.y : ((c==2) ? b.z : b.w));
      if (ALL || bv > -1e8f) {                // edge (bias == 0.0f)
        int j = (j4 << 2) + c;
        float x = s1v + s2[j];
        x = (x >= 0.f) ? x : 0.2f * x;        // leaky_relu 0.2
        float p;
        if (x > m) {
          float sc = __expf(m - x);           // m==-inf -> 0
          s *= sc;
          #pragma unroll
          for (int d = 0; d < 16; ++d) acc[d] *= sc;
          m = x; p = 1.f;
        } else {
          p = __expf(x - m);
        }
        s += p;
        const float4* whr = (const float4*)(wh + (size_t)j * 16);
        float4 w0 = whr[0], w1 = whr[1], w2 = whr[2], w3 = whr[3];
        acc[0]  += p*w0.x; acc[1]  += p*w0.y; acc[2]  += p*w0.z; acc[3]  += p*w0.w;
        acc[4]  += p*w1.x; acc[5]  += p*w1.y; acc[6]  += p*w1.z; acc[7]  += p*w1.w;
        acc[8]  += p*w2.x; acc[9]  += p*w2.y; acc[10] += p*w2.z; acc[11] += p*w2.w;
        acc[12] += p*w3.x; acc[13] += p*w3.y; acc[14] += p*w3.z; acc[15] += p*w3.w;
      }
    }
  }
}

__device__ __forceinline__ void merge_lanes(float& m, float& s, float acc[16])
{
  #pragma unroll
  for (int off = 32; off; off >>= 1) {
    float om = __shfl_xor(m, off);
    float os = __shfl_xor(s, off);
    float M2 = fmaxf(m, om);
    float ea = (m  >= M2) ? 1.f : __expf(m  - M2);
    float eb = (om >= M2) ? 1.f : __expf(om - M2);
    s = s * ea + os * eb;
    #pragma unroll
    for (int d = 0; d < 16; ++d) {
      float oa = __shfl_xor(acc[d], off);
      acc[d] = acc[d] * ea + oa * eb;
    }
    m = M2;
  }
}

__global__ __launch_bounds__(256) void att_kernel(const float* __restrict__ bias,
    const float* __restrict__ s1, const float* __restrict__ s2,
    const float* __restrict__ wh, float* __restrict__ head)
{
  const int lane = threadIdx.x & 63;
  const int row = (blockIdx.x << 2) + (threadIdx.x >> 6);   // (g*2+r)*ND + n
  const int n = row % ND;
  const float* brow = bias + (size_t)row * ND;
  const float s1v = s1[n];
  float m = -INFINITY, s = 0.f;
  float acc[16] = {};
  scan_row<false>(brow, s2, wh, s1v, lane, m, s, acc);
  merge_lanes(m, s, acc);
  if (s == 0.f) {   // pathological: row has no edges -> softmax over all entries
    m = -INFINITY; s = 0.f;
    #pragma unroll
    for (int d = 0; d < 16; ++d) acc[d] = 0.f;
    scan_row<true>(brow, s2, wh, s1v, lane, m, s, acc);
    merge_lanes(m, s, acc);
  }
  if (lane < 16) {
    float v = acc[0];
    #pragma unroll
    for (int d = 1; d < 16; ++d) if (lane == d) v = acc[d];   // static-index select
    v /= s;
    head[(size_t)row * 16 + lane] = (v > 0.f) ? v : expm1f(v);  // elu
  }
}

// ---------------- semantic attention per (g,n): 2 groups of 128 threads per block ----------------
__global__ __launch_bounds__(256) void sem_kernel(const float* __restrict__ head,
    const float* __restrict__ aws, const float* __restrict__ att_b,
    const float* __restrict__ att_u, const float* __restrict__ aom,
    float* __restrict__ pg, float* __restrict__ dots)
{
  __shared__ float AWS[2048];
  __shared__ float AB[128], AU[128], AOM[16];
  __shared__ float hsh[2][2][16];
  __shared__ float wred[4][2];
  const int t = threadIdx.x;
  for (int i = t; i < 2048; i += 256) AWS[i] = aws[i];
  if (t < 128) { AB[t] = att_b[t]; AU[t] = att_u[t]; }
  if (t < 16) AOM[t] = aom[t];
  const int grp = t >> 7, o = t & 127;
  const int gn = (blockIdx.x << 1) + grp;      // 0 .. 2*ND-1
  const int g = gn / ND, n = gn % ND;
  if (o < 32) {
    int r = o >> 4, d = o & 15;
    hsh[grp][r][d] = head[((size_t)(g*2 + r) * ND + n) * 16 + d];
  }
  __syncthreads();
  #pragma unroll
  for (int r = 0; r < 2; ++r) {
    float a = AB[o];
    #pragma unroll
    for (int d = 0; d < 16; ++d) a += hsh[grp][r][d] * AWS[d*128 + o];
    float v = tanhf(a) * AU[o];
    #pragma unroll
    for (int off = 32; off; off >>= 1) v += __shfl_xor(v, off);
    if ((t & 63) == 0) wred[t >> 6][r] = v;
  }
  __syncthreads();
  float t0 = wred[grp*2][0] + wred[grp*2 + 1][0];
  float t1 = wred[grp*2][1] + wred[grp*2 + 1][1];
  float mx = fmaxf(t0, t1);
  float e0 = __expf(t0 - mx), e1 = __expf(t1 - mx);
  float inv = 1.f / (e0 + e1);
  float a0 = e0 * inv, a1 = e1 * inv;
  if (o < 16) {
    float pv = a0 * hsh[grp][0][o] + a1 * hsh[grp][1][o];
    pg[((size_t)g * ND + n) * 16 + o] = pv;
    float contrib = pv * AOM[o];
    #pragma unroll
    for (int off = 8; off; off >>= 1) contrib += __shfl_xor(contrib, off);
    if (o == 0) dots[(size_t)g * ND + n] = contrib;
  }
}

// ---------------- deterministic reduce of dots -> gsum[g] ----------------
__global__ __launch_bounds__(256) void reduce_gsum(const float* __restrict__ dots,
    float* __restrict__ gsum)
{
  const int g = blockIdx.x, t = threadIdx.x;
  float v = 0.f;
  for (int i = t; i < ND; i += 256) v += dots[(size_t)g * ND + i];
  __shared__ float red[4];
  #pragma unroll
  for (int off = 32; off; off >>= 1) v += __shfl_xor(v, off);
  if ((t & 63) == 0) red[t >> 6] = v;
  __syncthreads();
  if (t == 0) gsum[g] = red[0] + red[1] + red[2] + red[3];
}

// ---------------- graph-weight softmax + combine: f16[n,d] = sum_g w_g * pg[g,n,d] ----------------
__global__ __launch_bounds__(256) void finalize_kernel(const float* __restrict__ pg,
    const float* __restrict__ gsum, float* __restrict__ f16)
{
  float g0 = gsum[0] * (1.f/ND), g1 = gsum[1] * (1.f/ND);
  float mx = fmaxf(g0, g1);
  float e0 = __expf(g0 - mx), e1 = __expf(g1 - mx);
  float w0 = e0 / (e0 + e1), w1 = e1 / (e0 + e1);
  int i = blockIdx.x * 256 + threadIdx.x;
  if (i < ND*16) f16[i] = w0 * pg[i] + w1 * pg[ND*16 + i];
}

// ---------------- fold rank-16 tiling into att_w / dec_w1 / a_omega ----------------
__global__ __launch_bounds__(256) void prep_kernel(const float* __restrict__ att_w,
    const float* __restrict__ dec_w1, const float* __restrict__ a_omega,
    float* __restrict__ aws, float* __restrict__ W1d, float* __restrict__ W1t,
    float* __restrict__ aom)
{
  const int t = threadIdx.x;
  for (int i = t; i < 2048; i += 256) {
    int d = i >> 7, o = i & 127;
    float sum = 0.f;
    #pragma unroll
    for (int tt = 0; tt < 8; ++tt) sum += att_w[(tt*16 + d)*128 + o];
    aws[i] = sum;
  }
  for (int i = t; i < 1024; i += 256) {
    int d = i >> 6, o = i & 63;
    float sd = 0.f, st = 0.f;
    #pragma unroll
    for (int tt = 0; tt < 8; ++tt) {
      sd += dec_w1[(tt*16 + d)*64 + o];
      st += dec_w1[(128 + tt*16 + d)*64 + o];
    }
    W1d[i] = sd; W1t[i] = st;
  }
  if (t < 16) {
    float sum = 0.f;
    #pragma unroll
    for (int tt = 0; tt < 8; ++tt) sum += a_omega[tt*16 + t];
    aom[t] = sum;
  }
}

// ---------------- decoder: per-edge [32]->64 relu ->1 sigmoid ----------------
__global__ __launch_bounds__(256) void dec_kernel(const int* __restrict__ ei,
    const float* __restrict__ f16d, const float* __restrict__ f16t,
    const float* __restrict__ W1d, const float* __restrict__ W1t,
    const float* __restrict__ b1, const float* __restrict__ w2,
    const float* __restrict__ b2, float* __restrict__ out)
{
  __shared__ float WdT[64][16], WtT[64][16];
  __shared__ float B1[64], W2s[64];
  const int t = threadIdx.x;
  for (int i = t; i < 1024; i += 256) {
    int d = i >> 6, o = i & 63;
    WdT[o][d] = W1d[i];
    WtT[o][d] = W1t[i];
  }
  if (t < 64) { B1[t] = b1[t]; W2s[t] = w2[t]; }
  __syncthreads();
  const int e = blockIdx.x * 256 + t;
  if (e >= EDG) return;
  const int i0 = ei[e], i1 = ei[EDG + e];
  const float4* pd = (const float4*)(f16d + (size_t)i0 * 16);
  const float4* pt = (const float4*)(f16t + (size_t)i1 * 16);
  float4 d0 = pd[0], d1 = pd[1], d2 = pd[2], d3 = pd[3];
  float4 e0 = pt[0], e1 = pt[1], e2 = pt[2], e3 = pt[3];
  float outv = b2[0];
  #pragma unroll 4
  for (int o = 0; o < 64; ++o) {
    const float4* wd = (const float4*)&WdT[o][0];
    const float4* wt = (const float4*)&WtT[o][0];
    float4 wd0 = wd[0], wd1 = wd[1], wd2 = wd[2], wd3 = wd[3];
    float4 wt0 = wt[0], wt1 = wt[1], wt2 = wt[2], wt3 = wt[3];
    float a = B1[o];
    a += d0.x*wd0.x + d0.y*wd0.y + d0.z*wd0.z + d0.w*wd0.w;
    a += d1.x*wd1.x + d1.y*wd1.y + d1.z*wd1.z + d1.w*wd1.w;
    a += d2.x*wd2.x + d2.y*wd2.y + d2.z*wd2.z + d2.w*wd2.w;
    a += d3.x*wd3.x + d3.y*wd3.y + d3.z*wd3.z + d3.w*wd3.w;
    a += e0.x*wt0.x + e0.y*wt0.y + e0.z*wt0.z + e0.w*wt0.w;
    a += e1.x*wt1.x + e1.y*wt1.y + e1.z*wt1.z + e1.w*wt1.w;
    a += e2.x*wt2.x + e2.y*wt2.y + e2.z*wt2.z + e2.w*wt2.w;
    a += e3.x*wt3.x + e3.y*wt3.y + e3.z*wt3.z + e3.w*wt3.w;
    a = fmaxf(a, 0.f);
    outv += a * W2s[o];
  }
  out[e] = 1.f / (1.f + __expf(-outv));
}

// ---------------- launch ----------------
extern "C" void kernel_launch(void* const* d_in, const int* in_sizes, int n_in,
                              void* d_out, int out_size, void* d_ws, size_t ws_size,
                              hipStream_t stream)
{
  const float* x_drug   = (const float*)d_in[0];
  const float* x_target = (const float*)d_in[1];
  const float* bias_d   = (const float*)d_in[2];
  const float* bias_t   = (const float*)d_in[3];
  const int*   ei       = (const int*)d_in[4];
  const float* dnn_w1 = (const float*)d_in[5];  const float* dnn_b1 = (const float*)d_in[6];
  const float* dnn_w2 = (const float*)d_in[7];  const float* dnn_b2 = (const float*)d_in[8];
  const float* dnn_w3 = (const float*)d_in[9];  const float* dnn_b3 = (const float*)d_in[10];
  const float* tnn_w1 = (const float*)d_in[11]; const float* tnn_b1 = (const float*)d_in[12];
  const float* tnn_w2 = (const float*)d_in[13]; const float* tnn_b2 = (const float*)d_in[14];
  const float* tnn_w3 = (const float*)d_in[15]; const float* tnn_b3 = (const float*)d_in[16];
  const float* gat_w  = (const float*)d_in[17];
  const float* gat_a1 = (const float*)d_in[18];
  const float* gat_a2 = (const float*)d_in[19];
  const float* att_w  = (const float*)d_in[20];
  const float* att_b  = (const float*)d_in[21];
  const float* att_u  = (const float*)d_in[22];
  const float* a_omega= (const float*)d_in[23];
  const float* dec_w1 = (const float*)d_in[24]; const float* dec_b1 = (const float*)d_in[25];
  const float* dec_w2 = (const float*)d_in[26]; const float* dec_b2 = (const float*)d_in[27];
  float* out = (float*)d_out;
  float* ws = (float*)d_ws;

  float* h1    = ws + OFF_H1;
  float* h2    = ws + OFF_H2;
  float* featD = ws + OFF_FEATD;
  float* featT = ws + OFF_FEATT;
  float* whD   = ws + OFF_WHD;
  float* whT   = ws + OFF_WHT;
  float* s1D   = ws + OFF_S1D; float* s2D = ws + OFF_S2D;
  float* s1T   = ws + OFF_S1T; float* s2T = ws + OFF_S2T;
  float* headD = ws + OFF_HEADD;
  float* headT = ws + OFF_HEADT;
  float* pgD   = ws + OFF_PGD;
  float* pgT   = ws + OFF_PGT;
  float* f16D  = ws + OFF_F16D;
  float* f16T  = ws + OFF_F16T;
  float* aws   = ws + OFF_AWS;
  float* W1d   = ws + OFF_W1D;
  float* W1t   = ws + OFF_W1T;
  float* aom   = ws + OFF_AOM;
  float* dotsD = ws + OFF_DOTSD;
  float* dotsT = ws + OFF_DOTST;
  float* gsumD = ws + OFF_GSUMD;
  float* gsumT = ws + OFF_GSUMT;

  prep_kernel<<<1, 256, 0, stream>>>(att_w, dec_w1, a_omega, aws, W1d, W1t, aom);

  // drug MLP: 1024 -> 512 -> 256 -> 128
  gemm_relu<<<dim3(8, 48), 256, 0, stream>>>(x_drug, dnn_w1, dnn_b1, h1, 3072, 512, 1024);
  gemm_relu<<<dim3(4, 48), 256, 0, stream>>>(h1, dnn_w2, dnn_b2, h2, 3072, 256, 512);
  gemm_relu<<<dim3(2, 48), 256, 0, stream>>>(h2, dnn_w3, dnn_b3, featD, 3072, 128, 256);
  // target MLP: 1280 -> 512 -> 256 -> 128
  gemm_relu<<<dim3(8, 48), 256, 0, stream>>>(x_target, tnn_w1, tnn_b1, h1, 3072, 512, 1280);
  gemm_relu<<<dim3(4, 48), 256, 0, stream>>>(h1, tnn_w2, tnn_b2, h2, 3072, 256, 512);
  gemm_relu<<<dim3(2, 48), 256, 0, stream>>>(h2, tnn_w3, tnn_b3, featT, 3072, 128, 256);

  wh_kernel<<<192, 256, 0, stream>>>(featD, gat_w, gat_a1, gat_a2, whD, s1D, s2D);
  wh_kernel<<<192, 256, 0, stream>>>(featT, gat_w, gat_a1, gat_a2, whT, s1T, s2T);

  att_kernel<<<3072, 256, 0, stream>>>(bias_d, s1D, s2D, whD, headD);
  att_kernel<<<3072, 256, 0, stream>>>(bias_t, s1T, s2T, whT, headT);

  sem_kernel<<<3072, 256, 0, stream>>>(headD, aws, att_b, att_u, aom, pgD, dotsD);
  sem_kernel<<<3072, 256, 0, stream>>>(headT, aws, att_b, att_u, aom, pgT, dotsT);

  reduce_gsum<<<2, 256, 0, stream>>>(dotsD, gsumD);
  reduce_gsum<<<2, 256, 0, stream>>>(dotsT, gsumT);

  finalize_kernel<<<192, 256, 0, stream>>>(pgD, gsumD, f16D);
  finalize_kernel<<<192, 256, 0, stream>>>(pgT, gsumT, f16T);

  dec_kernel<<<(EDG + 255) / 256, 256, 0, stream>>>(ei, f16D, f16T, W1d, W1t,
                                                    dec_b1, dec_w2, dec_b2, out);
}

// Round 2
// 423.985 us; speedup vs baseline: 1.2109x; 1.2109x over previous
//
#include <hip/hip_runtime.h>
#include <math.h>

#define ND 3072
#define EDG 100000
#define MAXE 128

// ---------------- workspace layout (float offsets) ----------------
enum : size_t {
  OFF_H1    = 0,                          // 3072*512  (reused for edge idx after MLPs)
  OFF_H2    = OFF_H1 + 3072*512,          // 3072*256  (reused for edge counts after MLPs)
  OFF_FEATD = OFF_H2 + 3072*256,          // 3072*128
  OFF_FEATT = OFF_FEATD + 3072*128,       // 3072*128
  OFF_WHD   = OFF_FEATT + 3072*128,       // 3072*16
  OFF_WHT   = OFF_WHD + 3072*16,
  OFF_S1D   = OFF_WHT + 3072*16,
  OFF_S2D   = OFF_S1D + 3072,
  OFF_S1T   = OFF_S2D + 3072,
  OFF_S2T   = OFF_S1T + 3072,
  OFF_HEADD = OFF_S2T + 3072,             // [2,2,3072,16]
  OFF_HEADT = OFF_HEADD + 4*3072*16,
  OFF_PGD   = OFF_HEADT + 4*3072*16,      // [2,3072,16]
  OFF_PGT   = OFF_PGD + 2*3072*16,
  OFF_F16D  = OFF_PGT + 2*3072*16,        // [3072,16]
  OFF_F16T  = OFF_F16D + 3072*16,
  OFF_AWS   = OFF_F16T + 3072*16,         // [16][128]
  OFF_W1D   = OFF_AWS + 2048,             // [16][64]
  OFF_W1T   = OFF_W1D + 1024,             // [16][64]
  OFF_AOM   = OFF_W1T + 1024,             // [16]
  OFF_DOTSD = OFF_AOM + 16,               // [2][3072]
  OFF_DOTST = OFF_DOTSD + 2*3072,
  OFF_GSUMD = OFF_DOTST + 2*3072,         // [2] (+pad)
  OFF_GSUMT = OFF_GSUMD + 4,
  OFF_S2MD  = OFF_GSUMT + 4,
  OFF_S2MT  = OFF_S2MD + 1,
  WS_TOTAL  = OFF_S2MT + 1
};

// ---------------- fused GEMM + bias + relu:  C[M,N] = relu(A[M,K]@B[K,N]+b) ----------------
__global__ __launch_bounds__(256) void gemm_relu(const float* __restrict__ A,
    const float* __restrict__ B, const float* __restrict__ bias,
    float* __restrict__ C, int M, int N, int K)
{
  __shared__ float AsT[32][68];   // K-major A tile, padded
  __shared__ float Bs[32][64];
  const int t  = threadIdx.x;
  const int tx = t & 15, ty = t >> 4;
  const int row0 = blockIdx.y << 6, col0 = blockIdx.x << 6;
  float acc[4][4] = {};
  const int ar0 = t >> 3, ac0 = (t & 7) << 2;
  const int ar1 = ar0 + 32;
  const int br0 = t >> 4, bc0 = (t & 15) << 2;
  const int br1 = br0 + 16;
  for (int k0 = 0; k0 < K; k0 += 32) {
    float4 a0 = *(const float4*)&A[(size_t)(row0 + ar0) * K + k0 + ac0];
    float4 a1 = *(const float4*)&A[(size_t)(row0 + ar1) * K + k0 + ac0];
    float4 b0 = *(const float4*)&B[(size_t)(k0 + br0) * N + col0 + bc0];
    float4 b1 = *(const float4*)&B[(size_t)(k0 + br1) * N + col0 + bc0];
    __syncthreads();
    AsT[ac0+0][ar0]=a0.x; AsT[ac0+1][ar0]=a0.y; AsT[ac0+2][ar0]=a0.z; AsT[ac0+3][ar0]=a0.w;
    AsT[ac0+0][ar1]=a1.x; AsT[ac0+1][ar1]=a1.y; AsT[ac0+2][ar1]=a1.z; AsT[ac0+3][ar1]=a1.w;
    *(float4*)&Bs[br0][bc0] = b0;
    *(float4*)&Bs[br1][bc0] = b1;
    __syncthreads();
    #pragma unroll
    for (int kk = 0; kk < 32; ++kk) {
      float4 av = *(const float4*)&AsT[kk][ty << 2];
      float4 bv = *(const float4*)&Bs[kk][tx << 2];
      acc[0][0] += av.x*bv.x; acc[0][1] += av.x*bv.y; acc[0][2] += av.x*bv.z; acc[0][3] += av.x*bv.w;
      acc[1][0] += av.y*bv.x; acc[1][1] += av.y*bv.y; acc[1][2] += av.y*bv.z; acc[1][3] += av.y*bv.w;
      acc[2][0] += av.z*bv.x; acc[2][1] += av.z*bv.y; acc[2][2] += av.z*bv.z; acc[2][3] += av.z*bv.w;
      acc[3][0] += av.w*bv.x; acc[3][1] += av.w*bv.y; acc[3][2] += av.w*bv.z; acc[3][3] += av.w*bv.w;
    }
  }
  float4 bb = *(const float4*)&bias[col0 + (tx << 2)];
  #pragma unroll
  for (int i = 0; i < 4; ++i) {
    int row = row0 + (ty << 2) + i;
    float4 o;
    o.x = fmaxf(acc[i][0] + bb.x, 0.f);
    o.y = fmaxf(acc[i][1] + bb.y, 0.f);
    o.z = fmaxf(acc[i][2] + bb.z, 0.f);
    o.w = fmaxf(acc[i][3] + bb.w, 0.f);
    *(float4*)&C[(size_t)row * N + col0 + (tx << 2)] = o;
  }
}

// ---------------- wh = feats@gat_w [N,16]; s1 = wh@a1; s2 = wh@a2 ----------------
__global__ __launch_bounds__(256) void wh_kernel(const float* __restrict__ feat,
    const float* __restrict__ gw, const float* __restrict__ ga1, const float* __restrict__ ga2,
    float* __restrict__ wh, float* __restrict__ s1, float* __restrict__ s2)
{
  __shared__ float W[128*16];
  __shared__ float A1[16], A2[16];
  const int t = threadIdx.x;
  for (int i = t; i < 2048; i += 256) W[i] = gw[i];
  if (t < 16) { A1[t] = ga1[t]; A2[t] = ga2[t]; }
  __syncthreads();
  const int n = (blockIdx.x << 4) + (t >> 4);
  const int d = t & 15;
  const float* f = feat + (size_t)n * 128;
  float acc = 0.f;
  #pragma unroll 8
  for (int k = 0; k < 128; ++k) acc += f[k] * W[k*16 + d];
  wh[(size_t)n*16 + d] = acc;
  float v1 = acc * A1[d], v2 = acc * A2[d];
  #pragma unroll
  for (int off = 8; off; off >>= 1) { v1 += __shfl_xor(v1, off); v2 += __shfl_xor(v2, off); }
  if (d == 0) { s1[n] = v1; s2[n] = v2; }
}

// ---------------- global max of s2 (single scalar upper bound for row maxes) ----------------
__global__ __launch_bounds__(256) void max_kernel(const float* __restrict__ s2,
    float* __restrict__ out)
{
  const int t = threadIdx.x;
  float m = -INFINITY;
  for (int i = t; i < ND; i += 256) m = fmaxf(m, s2[i]);
  #pragma unroll
  for (int off = 32; off; off >>= 1) m = fmaxf(m, __shfl_xor(m, off));
  __shared__ float red[4];
  if ((t & 63) == 0) red[t >> 6] = m;
  __syncthreads();
  if (t == 0) out[0] = fmaxf(fmaxf(red[0], red[1]), fmaxf(red[2], red[3]));
}

// ---------------- phase A: stream bias, compact edge column indices per row ----------------
__global__ __launch_bounds__(256) void scan_kernel(const float* __restrict__ bias,
    unsigned short* __restrict__ idx, int* __restrict__ cnts)
{
  const int lane = threadIdx.x & 63;
  const int row = (blockIdx.x << 2) + (threadIdx.x >> 6);   // (g*2+r)*ND + n
  const float4* brow = (const float4*)(bias + (size_t)row * ND);
  unsigned short* ei = idx + (size_t)row * MAXE;
  const unsigned long long ltmask = (1ull << lane) - 1ull;
  int cnt = 0;
  #pragma unroll 3
  for (int i = 0; i < ND/256; ++i) {
    const int j4 = lane + (i << 6);
    float4 b = brow[j4];
    #pragma unroll
    for (int c = 0; c < 4; ++c) {
      float bv = (c==0) ? b.x : ((c==1) ? b.y : ((c==2) ? b.z : b.w));
      bool e = bv > -1e8f;
      unsigned long long mask = __ballot(e);
      if (e) {
        int pos = cnt + __popcll(mask & ltmask);
        if (pos < MAXE) ei[pos] = (unsigned short)((j4 << 2) + c);
      }
      cnt += __popcll(mask);
    }
  }
  if (lane == 0) cnts[row] = cnt < MAXE ? cnt : MAXE;
}

// ---------------- phase B: softmax-weighted aggregation over compacted edges ----------------
__global__ __launch_bounds__(256) void acc_kernel(const unsigned short* __restrict__ idx,
    const int* __restrict__ cnts, const float* __restrict__ s1, const float* __restrict__ s2,
    const float* __restrict__ s2max, const float* __restrict__ wh, float* __restrict__ head)
{
  const int lane = threadIdx.x & 63;
  const int row = (blockIdx.x << 2) + (threadIdx.x >> 6);
  const int n = row % ND;
  const int eg = lane >> 4, d = lane & 15;
  const float s1v = s1[n];
  float mn = s1v + s2max[0];
  mn = (mn >= 0.f) ? mn : 0.2f * mn;          // lrelu(s1 + max s2) >= row max
  const unsigned short* ei = idx + (size_t)row * MAXE;
  const int cnt = cnts[row];
  float acc = 0.f, ss = 0.f;
  if (cnt > 0) {
    for (int slot = eg; slot < cnt; slot += 4) {
      int j = ei[slot];
      float x = s1v + s2[j];
      x = (x >= 0.f) ? x : 0.2f * x;
      float p = __expf(x - mn);
      ss += p;
      acc += p * wh[j*16 + d];
    }
  } else {                                    // no edges: softmax over all columns
    for (int j = eg; j < ND; j += 4) {
      float x = s1v + s2[j];
      x = (x >= 0.f) ? x : 0.2f * x;
      float p = __expf(x - mn);
      ss += p;
      acc += p * wh[j*16 + d];
    }
  }
  acc += __shfl_xor(acc, 16); acc += __shfl_xor(acc, 32);
  ss  += __shfl_xor(ss, 16);  ss  += __shfl_xor(ss, 32);
  if (lane < 16) {
    float v = acc / ss;
    head[(size_t)row * 16 + lane] = (v > 0.f) ? v : expm1f(v);   // elu
  }
}

// ---------------- semantic attention per (g,n) ----------------
__global__ __launch_bounds__(256) void sem_kernel(const float* __restrict__ head,
    const float* __restrict__ aws, const float* __restrict__ att_b,
    const float* __restrict__ att_u, const float* __restrict__ aom,
    float* __restrict__ pg, float* __restrict__ dots)
{
  __shared__ float AWS[2048];
  __shared__ float AB[128], AU[128], AOM[16];
  __shared__ float hsh[2][2][16];
  __shared__ float wred[4][2];
  const int t = threadIdx.x;
  for (int i = t; i < 2048; i += 256) AWS[i] = aws[i];
  if (t < 128) { AB[t] = att_b[t]; AU[t] = att_u[t]; }
  if (t < 16) AOM[t] = aom[t];
  const int grp = t >> 7, o = t & 127;
  const int gn = (blockIdx.x << 1) + grp;
  const int g = gn / ND, n = gn % ND;
  if (o < 32) {
    int r = o >> 4, d = o & 15;
    hsh[grp][r][d] = head[((size_t)(g*2 + r) * ND + n) * 16 + d];
  }
  __syncthreads();
  #pragma unroll
  for (int r = 0; r < 2; ++r) {
    float a = AB[o];
    #pragma unroll
    for (int d = 0; d < 16; ++d) a += hsh[grp][r][d] * AWS[d*128 + o];
    float v = tanhf(a) * AU[o];
    #pragma unroll
    for (int off = 32; off; off >>= 1) v += __shfl_xor(v, off);
    if ((t & 63) == 0) wred[t >> 6][r] = v;
  }
  __syncthreads();
  float t0 = wred[grp*2][0] + wred[grp*2 + 1][0];
  float t1 = wred[grp*2][1] + wred[grp*2 + 1][1];
  float mx = fmaxf(t0, t1);
  float e0 = __expf(t0 - mx), e1 = __expf(t1 - mx);
  float inv = 1.f / (e0 + e1);
  float a0 = e0 * inv, a1 = e1 * inv;
  if (o < 16) {
    float pv = a0 * hsh[grp][0][o] + a1 * hsh[grp][1][o];
    pg[((size_t)g * ND + n) * 16 + o] = pv;
    float contrib = pv * AOM[o];
    #pragma unroll
    for (int off = 8; off; off >>= 1) contrib += __shfl_xor(contrib, off);
    if (o == 0) dots[(size_t)g * ND + n] = contrib;
  }
}

// ---------------- deterministic reduce of dots -> gsum[g] ----------------
__global__ __launch_bounds__(256) void reduce_gsum(const float* __restrict__ dots,
    float* __restrict__ gsum)
{
  const int g = blockIdx.x, t = threadIdx.x;
  float v = 0.f;
  for (int i = t; i < ND; i += 256) v += dots[(size_t)g * ND + i];
  __shared__ float red[4];
  #pragma unroll
  for (int off = 32; off; off >>= 1) v += __shfl_xor(v, off);
  if ((t & 63) == 0) red[t >> 6] = v;
  __syncthreads();
  if (t == 0) gsum[g] = red[0] + red[1] + red[2] + red[3];
}

// ---------------- graph-weight softmax + combine ----------------
__global__ __launch_bounds__(256) void finalize_kernel(const float* __restrict__ pg,
    const float* __restrict__ gsum, float* __restrict__ f16)
{
  float g0 = gsum[0] * (1.f/ND), g1 = gsum[1] * (1.f/ND);
  float mx = fmaxf(g0, g1);
  float e0 = __expf(g0 - mx), e1 = __expf(g1 - mx);
  float w0 = e0 / (e0 + e1), w1 = e1 / (e0 + e1);
  int i = blockIdx.x * 256 + threadIdx.x;
  if (i < ND*16) f16[i] = w0 * pg[i] + w1 * pg[ND*16 + i];
}

// ---------------- fold rank-16 tiling into att_w / dec_w1 / a_omega ----------------
__global__ __launch_bounds__(256) void prep_kernel(const float* __restrict__ att_w,
    const float* __restrict__ dec_w1, const float* __restrict__ a_omega,
    float* __restrict__ aws, float* __restrict__ W1d, float* __restrict__ W1t,
    float* __restrict__ aom)
{
  const int t = threadIdx.x;
  for (int i = t; i < 2048; i += 256) {
    int d = i >> 7, o = i & 127;
    float sum = 0.f;
    #pragma unroll
    for (int tt = 0; tt < 8; ++tt) sum += att_w[(tt*16 + d)*128 + o];
    aws[i] = sum;
  }
  for (int i = t; i < 1024; i += 256) {
    int d = i >> 6, o = i & 63;
    float sd = 0.f, st = 0.f;
    #pragma unroll
    for (int tt = 0; tt < 8; ++tt) {
      sd += dec_w1[(tt*16 + d)*64 + o];
      st += dec_w1[(128 + tt*16 + d)*64 + o];
    }
    W1d[i] = sd; W1t[i] = st;
  }
  if (t < 16) {
    float sum = 0.f;
    #pragma unroll
    for (int tt = 0; tt < 8; ++tt) sum += a_omega[tt*16 + t];
    aom[t] = sum;
  }
}

// ---------------- decoder: per-edge [32]->64 relu ->1 sigmoid ----------------
__global__ __launch_bounds__(256) void dec_kernel(const int* __restrict__ ei,
    const float* __restrict__ f16d, const float* __restrict__ f16t,
    const float* __restrict__ W1d, const float* __restrict__ W1t,
    const float* __restrict__ b1, const float* __restrict__ w2,
    const float* __restrict__ b2, float* __restrict__ out)
{
  __shared__ float WdT[64][16], WtT[64][16];
  __shared__ float B1[64], W2s[64];
  const int t = threadIdx.x;
  for (int i = t; i < 1024; i += 256) {
    int d = i >> 6, o = i & 63;
    WdT[o][d] = W1d[i];
    WtT[o][d] = W1t[i];
  }
  if (t < 64) { B1[t] = b1[t]; W2s[t] = w2[t]; }
  __syncthreads();
  const int e = blockIdx.x * 256 + t;
  if (e >= EDG) return;
  const int i0 = ei[e], i1 = ei[EDG + e];
  const float4* pd = (const float4*)(f16d + (size_t)i0 * 16);
  const float4* pt = (const float4*)(f16t + (size_t)i1 * 16);
  float4 d0 = pd[0], d1 = pd[1], d2 = pd[2], d3 = pd[3];
  float4 e0 = pt[0], e1 = pt[1], e2 = pt[2], e3 = pt[3];
  float outv = b2[0];
  #pragma unroll 4
  for (int o = 0; o < 64; ++o) {
    const float4* wd = (const float4*)&WdT[o][0];
    const float4* wt = (const float4*)&WtT[o][0];
    float4 wd0 = wd[0], wd1 = wd[1], wd2 = wd[2], wd3 = wd[3];
    float4 wt0 = wt[0], wt1 = wt[1], wt2 = wt[2], wt3 = wt[3];
    float a = B1[o];
    a += d0.x*wd0.x + d0.y*wd0.y + d0.z*wd0.z + d0.w*wd0.w;
    a += d1.x*wd1.x + d1.y*wd1.y + d1.z*wd1.z + d1.w*wd1.w;
    a += d2.x*wd2.x + d2.y*wd2.y + d2.z*wd2.z + d2.w*wd2.w;
    a += d3.x*wd3.x + d3.y*wd3.y + d3.z*wd3.z + d3.w*wd3.w;
    a += e0.x*wt0.x + e0.y*wt0.y + e0.z*wt0.z + e0.w*wt0.w;
    a += e1.x*wt1.x + e1.y*wt1.y + e1.z*wt1.z + e1.w*wt1.w;
    a += e2.x*wt2.x + e2.y*wt2.y + e2.z*wt2.z + e2.w*wt2.w;
    a += e3.x*wt3.x + e3.y*wt3.y + e3.z*wt3.z + e3.w*wt3.w;
    a = fmaxf(a, 0.f);
    outv += a * W2s[o];
  }
  out[e] = 1.f / (1.f + __expf(-outv));
}

// ---------------- launch ----------------
extern "C" void kernel_launch(void* const* d_in, const int* in_sizes, int n_in,
                              void* d_out, int out_size, void* d_ws, size_t ws_size,
                              hipStream_t stream)
{
  const float* x_drug   = (const float*)d_in[0];
  const float* x_target = (const float*)d_in[1];
  const float* bias_d   = (const float*)d_in[2];
  const float* bias_t   = (const float*)d_in[3];
  const int*   ei       = (const int*)d_in[4];
  const float* dnn_w1 = (const float*)d_in[5];  const float* dnn_b1 = (const float*)d_in[6];
  const float* dnn_w2 = (const float*)d_in[7];  const float* dnn_b2 = (const float*)d_in[8];
  const float* dnn_w3 = (const float*)d_in[9];  const float* dnn_b3 = (const float*)d_in[10];
  const float* tnn_w1 = (const float*)d_in[11]; const float* tnn_b1 = (const float*)d_in[12];
  const float* tnn_w2 = (const float*)d_in[13]; const float* tnn_b2 = (const float*)d_in[14];
  const float* tnn_w3 = (const float*)d_in[15]; const float* tnn_b3 = (const float*)d_in[16];
  const float* gat_w  = (const float*)d_in[17];
  const float* gat_a1 = (const float*)d_in[18];
  const float* gat_a2 = (const float*)d_in[19];
  const float* att_w  = (const float*)d_in[20];
  const float* att_b  = (const float*)d_in[21];
  const float* att_u  = (const float*)d_in[22];
  const float* a_omega= (const float*)d_in[23];
  const float* dec_w1 = (const float*)d_in[24]; const float* dec_b1 = (const float*)d_in[25];
  const float* dec_w2 = (const float*)d_in[26]; const float* dec_b2 = (const float*)d_in[27];
  float* out = (float*)d_out;
  float* ws = (float*)d_ws;

  float* h1    = ws + OFF_H1;
  float* h2    = ws + OFF_H2;
  float* featD = ws + OFF_FEATD;
  float* featT = ws + OFF_FEATT;
  float* whD   = ws + OFF_WHD;
  float* whT   = ws + OFF_WHT;
  float* s1D   = ws + OFF_S1D; float* s2D = ws + OFF_S2D;
  float* s1T   = ws + OFF_S1T; float* s2T = ws + OFF_S2T;
  float* headD = ws + OFF_HEADD;
  float* headT = ws + OFF_HEADT;
  float* pgD   = ws + OFF_PGD;
  float* pgT   = ws + OFF_PGT;
  float* f16D  = ws + OFF_F16D;
  float* f16T  = ws + OFF_F16T;
  float* aws   = ws + OFF_AWS;
  float* W1d   = ws + OFF_W1D;
  float* W1t   = ws + OFF_W1T;
  float* aom   = ws + OFF_AOM;
  float* dotsD = ws + OFF_DOTSD;
  float* dotsT = ws + OFF_DOTST;
  float* gsumD = ws + OFF_GSUMD;
  float* gsumT = ws + OFF_GSUMT;
  float* s2mD  = ws + OFF_S2MD;
  float* s2mT  = ws + OFF_S2MT;

  // edge buffers overlay h1/h2 (dead after the MLP GEMMs; stream is serial)
  unsigned short* eidxD = (unsigned short*)(ws + OFF_H1);
  unsigned short* eidxT = (unsigned short*)(ws + OFF_H1 + 4*3072*MAXE/2);  // 786432 floats each
  int* cntD = (int*)(ws + OFF_H2);
  int* cntT = (int*)(ws + OFF_H2 + 4*3072);

  prep_kernel<<<1, 256, 0, stream>>>(att_w, dec_w1, a_omega, aws, W1d, W1t, aom);

  // drug MLP: 1024 -> 512 -> 256 -> 128
  gemm_relu<<<dim3(8, 48), 256, 0, stream>>>(x_drug, dnn_w1, dnn_b1, h1, 3072, 512, 1024);
  gemm_relu<<<dim3(4, 48), 256, 0, stream>>>(h1, dnn_w2, dnn_b2, h2, 3072, 256, 512);
  gemm_relu<<<dim3(2, 48), 256, 0, stream>>>(h2, dnn_w3, dnn_b3, featD, 3072, 128, 256);
  // target MLP: 1280 -> 512 -> 256 -> 128
  gemm_relu<<<dim3(8, 48), 256, 0, stream>>>(x_target, tnn_w1, tnn_b1, h1, 3072, 512, 1280);
  gemm_relu<<<dim3(4, 48), 256, 0, stream>>>(h1, tnn_w2, tnn_b2, h2, 3072, 256, 512);
  gemm_relu<<<dim3(2, 48), 256, 0, stream>>>(h2, tnn_w3, tnn_b3, featT, 3072, 128, 256);

  wh_kernel<<<192, 256, 0, stream>>>(featD, gat_w, gat_a1, gat_a2, whD, s1D, s2D);
  wh_kernel<<<192, 256, 0, stream>>>(featT, gat_w, gat_a1, gat_a2, whT, s1T, s2T);
  max_kernel<<<1, 256, 0, stream>>>(s2D, s2mD);
  max_kernel<<<1, 256, 0, stream>>>(s2T, s2mT);

  scan_kernel<<<3072, 256, 0, stream>>>(bias_d, eidxD, cntD);
  scan_kernel<<<3072, 256, 0, stream>>>(bias_t, eidxT, cntT);
  acc_kernel<<<3072, 256, 0, stream>>>(eidxD, cntD, s1D, s2D, s2mD, whD, headD);
  acc_kernel<<<3072, 256, 0, stream>>>(eidxT, cntT, s1T, s2T, s2mT, whT, headT);

  sem_kernel<<<3072, 256, 0, stream>>>(headD, aws, att_b, att_u, aom, pgD, dotsD);
  sem_kernel<<<3072, 256, 0, stream>>>(headT, aws, att_b, att_u, aom, pgT, dotsT);

  reduce_gsum<<<2, 256, 0, stream>>>(dotsD, gsumD);
  reduce_gsum<<<2, 256, 0, stream>>>(dotsT, gsumT);

  finalize_kernel<<<192, 256, 0, stream>>>(pgD, gsumD, f16D);
  finalize_kernel<<<192, 256, 0, stream>>>(pgT, gsumT, f16T);

  dec_kernel<<<(EDG + 255) / 256, 256, 0, stream>>>(ei, f16D, f16T, W1d, W1t,
                                                    dec_b1, dec_w2, dec_b2, out);
}